// Round 1
// baseline (499.386 us; speedup 1.0000x reference)
//
#include <hip/hip_runtime.h>

typedef unsigned short u16;
typedef __attribute__((ext_vector_type(8))) short s16x8;
typedef __attribute__((ext_vector_type(4))) short s16x4;
typedef __attribute__((ext_vector_type(4))) float f32x4;

#define S_LEN 4096
#define D_DIM 1024
#define NH    16
#define HDIM  64

#define AS1 __attribute__((address_space(1)))
#define AS3 __attribute__((address_space(3)))

__device__ __forceinline__ u16 f2bf(float f) {
  unsigned u = __float_as_uint(f);
  u += 0x7FFF + ((u >> 16) & 1);   // RNE
  return (u16)(u >> 16);
}

// async global->LDS, 16B per lane; LDS dest must be wave-uniform (HW adds lane*16)
__device__ __forceinline__ void load_lds16(const void* g, void* l) {
  __builtin_amdgcn_global_load_lds((AS1 void*)g, (AS3 void*)l, 16, 0, 0);
}

__device__ __forceinline__ unsigned lds_addr32(const void* p) {
  return (unsigned)(unsigned long long)(AS3 const char*)p;
}

// hardware transpose read: lane l gets col (l&15), rows 4*(l>>4)+j of a
// row-major [16][16] bf16 subtile when per-lane addr = base + l*8
__device__ __forceinline__ s16x4 ds_read_tr16(unsigned addr) {
  s16x4 r;
  asm volatile("ds_read_b64_tr_b16 %0, %1" : "=v"(r) : "v"(addr));
  return r;
}

// ---------------- fp32 -> bf16 ----------------
__global__ __launch_bounds__(256) void cvt_bf16(const float* __restrict__ in,
                                                u16* __restrict__ out, int n) {
  int i = (blockIdx.x * 256 + threadIdx.x) * 4;
  if (i + 3 < n) {
    float4 v = *(const float4*)(in + i);
    ushort4 o;
    o.x = f2bf(v.x); o.y = f2bf(v.y); o.z = f2bf(v.z); o.w = f2bf(v.w);
    *(ushort4*)(out + i) = o;
  }
}

// ---------------- GEMM: C[M,N] = A[M,K] * B[N,K]^T (bf16 in, fp32 acc) ----------
// tile 128x64, BK=32, 4 waves (2x2), wave tile 64x32 (4x2 frags of 16x16)
struct GemmSmem { u16 As[128 * 32]; u16 Bs[64 * 32]; };

template <bool BF16_OUT>
__device__ __forceinline__ void gemm_tile(GemmSmem& sm, const u16* __restrict__ A,
                                          const u16* __restrict__ B,
                                          void* __restrict__ C, int m0, int n0,
                                          int N, int K) {
  const int t = threadIdx.x;
  const int l = t & 63, g = l >> 4, r = l & 15;
  const int w = t >> 6, wr = w >> 1, wc = w & 1;
  f32x4 acc[4][2] = {};
  for (int k0 = 0; k0 < K; k0 += 32) {
    __syncthreads();                       // previous tile's reads done
#pragma unroll
    for (int i = 0; i < 2; ++i) {          // A: 512 granules of 16B
      int gi = t + i * 256;
      const u16* ga = A + (size_t)(m0 + (gi >> 2)) * K + k0 + (gi & 3) * 8;
      load_lds16(ga, (char*)sm.As + (i * 256 + (t & 192)) * 16);
    }
    {                                       // B: 256 granules
      const u16* gb = B + (size_t)(n0 + (t >> 2)) * K + k0 + (t & 3) * 8;
      load_lds16(gb, (char*)sm.Bs + (t & 192) * 16);
    }
    __syncthreads();                        // staged data visible (vmcnt drained)
    s16x8 a[4], b[2];
#pragma unroll
    for (int m = 0; m < 4; ++m)
      a[m] = *(const s16x8*)&sm.As[(wr * 64 + m * 16 + r) * 32 + g * 8];
#pragma unroll
    for (int n = 0; n < 2; ++n)
      b[n] = *(const s16x8*)&sm.Bs[(wc * 32 + n * 16 + r) * 32 + g * 8];
#pragma unroll
    for (int m = 0; m < 4; ++m)
#pragma unroll
      for (int n = 0; n < 2; ++n)
        acc[m][n] = __builtin_amdgcn_mfma_f32_16x16x32_bf16(a[m], b[n], acc[m][n], 0, 0, 0);
  }
  // D layout (verified): col = lane&15, row = 4*(lane>>4) + reg
#pragma unroll
  for (int m = 0; m < 4; ++m)
#pragma unroll
    for (int n = 0; n < 2; ++n)
#pragma unroll
      for (int v = 0; v < 4; ++v) {
        int row = m0 + wr * 64 + m * 16 + g * 4 + v;
        int col = n0 + wc * 32 + n * 16 + r;
        if (BF16_OUT)
          ((u16*)C)[(size_t)row * N + col] = f2bf(acc[m][n][v]);
        else
          ((float*)C)[(size_t)row * N + col] = acc[m][n][v];
      }
}

__global__ __launch_bounds__(256) void gemm_qkv(const u16* __restrict__ A,
                                                const u16* __restrict__ Bq,
                                                const u16* __restrict__ Bk,
                                                const u16* __restrict__ Bv,
                                                u16* Cq, u16* Ck, u16* Cv_) {
  __shared__ GemmSmem sm;
  const int which = blockIdx.x >> 4;   // 16 n-blocks of 64 per matrix
  const u16* B = which == 0 ? Bq : (which == 1 ? Bk : Bv);
  u16* C = which == 0 ? Cq : (which == 1 ? Ck : Cv_);
  gemm_tile<true>(sm, A, B, C, blockIdx.y * 128, (blockIdx.x & 15) * 64, D_DIM, D_DIM);
}

__global__ __launch_bounds__(256) void gemm_out(const u16* __restrict__ A,
                                                const u16* __restrict__ B,
                                                float* __restrict__ C) {
  __shared__ GemmSmem sm;
  gemm_tile<false>(sm, A, B, C, blockIdx.y * 128, blockIdx.x * 64, D_DIM, D_DIM);
}

// ---------------- causal flash attention ----------------
// block = 4 waves, QBLK=64 (16 q-rows/wave), KVBLK=32, one (head, q-block) per block
__global__ __launch_bounds__(256) void flash_attn(const u16* __restrict__ Q,
                                                  const u16* __restrict__ Kg,
                                                  const u16* __restrict__ V,
                                                  u16* __restrict__ CTX) {
  const int h = blockIdx.y;
  const int qb = gridDim.x - 1 - blockIdx.x;  // big blocks first (causal tail)
  const int hoff = h * HDIM;
  const int t = threadIdx.x, w = t >> 6, l = t & 63, g = l >> 4, r = l & 15;
  const int q0 = qb * 64 + w * 16;

  __shared__ u16 Kt[32 * 64];     // [kv][hd], granule-XOR swizzled
  __shared__ u16 Vt[8 * 256];     // 8 subtiles [16kv][16hd] for tr-reads
  __shared__ u16 Pt[4][16 * 32];  // per-wave P

  // Q fragments (A-operand): row = q0+r, k = hd contiguous-8
  const u16* qrow = Q + (size_t)(q0 + r) * D_DIM + hoff;
  const s16x8 aq0 = *(const s16x8*)(qrow + g * 8);
  const s16x8 aq1 = *(const s16x8*)(qrow + 32 + g * 8);

  f32x4 o[4] = {};
  float mrow[4], lrow[4];
#pragma unroll
  for (int v = 0; v < 4; ++v) { mrow[v] = -1e30f; lrow[v] = 0.f; }

  // staging index precompute
  const int krow = t >> 3, kcs = (t & 7) ^ (krow & 7);           // K swizzle
  const int vb = t >> 5, vwg = t & 31;
  const int vkb = vb >> 2, vnb = vb & 3, vkv = vwg >> 1, vhd = (vwg & 1) * 8;

  const int ntiles = qb * 2 + 2;
  for (int tile = 0; tile < ntiles; ++tile) {
    const int kv0 = tile * 32;
    __syncthreads();
    {
      const u16* gk = Kg + (size_t)(kv0 + krow) * D_DIM + hoff + kcs * 8;
      load_lds16(gk, (char*)Kt + (t & 192) * 16);
      const u16* gv = V + (size_t)(kv0 + vkb * 16 + vkv) * D_DIM + hoff + vnb * 16 + vhd;
      load_lds16(gv, (char*)Vt + (t & 192) * 16);
    }
    __syncthreads();
    if (kv0 <= q0 + 15) {
      // ---- QK^T: S[16q x 32kv] ----
      f32x4 s[2];
#pragma unroll
      for (int nb = 0; nb < 2; ++nb) {
        const int kr = nb * 16 + r;
        s16x8 bk0 = *(const s16x8*)&Kt[kr * 64 + (((0 + g) ^ (kr & 7)) << 3)];
        s16x8 bk1 = *(const s16x8*)&Kt[kr * 64 + (((4 + g) ^ (kr & 7)) << 3)];
        f32x4 z = {0.f, 0.f, 0.f, 0.f};
        z = __builtin_amdgcn_mfma_f32_16x16x32_bf16(aq0, bk0, z, 0, 0, 0);
        z = __builtin_amdgcn_mfma_f32_16x16x32_bf16(aq1, bk1, z, 0, 0, 0);
        s[nb] = z;
      }
      // ---- online softmax (rows q = 4g+v, cols kv = nb*16+r) ----
      float p[2][4], tmax[4];
#pragma unroll
      for (int v = 0; v < 4; ++v) {
        const int qg = q0 + 4 * g + v;
#pragma unroll
        for (int nb = 0; nb < 2; ++nb) {
          float sv = s[nb][v] * 0.125f;
          if (kv0 + nb * 16 + r > qg) sv = -1e30f;   // causal mask
          p[nb][v] = sv;
        }
        tmax[v] = fmaxf(p[0][v], p[1][v]);
      }
#pragma unroll
      for (int off = 1; off < 16; off <<= 1)
#pragma unroll
        for (int v = 0; v < 4; ++v)
          tmax[v] = fmaxf(tmax[v], __shfl_xor(tmax[v], off, 64));
      float fs[4], tsum[4];
#pragma unroll
      for (int v = 0; v < 4; ++v) {
        const float mnew = fmaxf(mrow[v], tmax[v]);
        fs[v] = __expf(mrow[v] - mnew);
        mrow[v] = mnew;
        float ps = 0.f;
#pragma unroll
        for (int nb = 0; nb < 2; ++nb) {
          const float pv = __expf(p[nb][v] - mnew);
          p[nb][v] = pv;
          ps += pv;
        }
        tsum[v] = ps;
      }
#pragma unroll
      for (int off = 1; off < 16; off <<= 1)
#pragma unroll
        for (int v = 0; v < 4; ++v) tsum[v] += __shfl_xor(tsum[v], off, 64);
#pragma unroll
      for (int v = 0; v < 4; ++v) {
        lrow[v] = lrow[v] * fs[v] + tsum[v];
#pragma unroll
        for (int nb = 0; nb < 4; ++nb) o[nb][v] *= fs[v];
#pragma unroll
        for (int nb = 0; nb < 2; ++nb)
          Pt[w][(4 * g + v) * 32 + nb * 16 + r] = f2bf(p[nb][v]);
      }
      // ---- PV: ctx += P[16q x 32kv] * V[32kv x 64hd] ----
      s16x4 tv[4][2];
      const unsigned vbase = lds_addr32(Vt) + (unsigned)(l * 8);
#pragma unroll
      for (int nb = 0; nb < 4; ++nb)
#pragma unroll
        for (int kb = 0; kb < 2; ++kb)
          tv[nb][kb] = ds_read_tr16(vbase + (unsigned)((kb * 4 + nb) * 512));
      // P A-fragments: row=r, k = 4g+(e&3)+16*(e>>2)  (matches tr-read k-map)
      s16x4 plo = *(const s16x4*)&Pt[w][r * 32 + g * 4];
      s16x4 phi = *(const s16x4*)&Pt[w][r * 32 + 16 + g * 4];
      asm volatile("s_waitcnt lgkmcnt(0)" ::: "memory");
      __builtin_amdgcn_sched_barrier(0);
      s16x8 pa = {plo[0], plo[1], plo[2], plo[3], phi[0], phi[1], phi[2], phi[3]};
#pragma unroll
      for (int nb = 0; nb < 4; ++nb) {
        s16x8 bv = {tv[nb][0][0], tv[nb][0][1], tv[nb][0][2], tv[nb][0][3],
                    tv[nb][1][0], tv[nb][1][1], tv[nb][1][2], tv[nb][1][3]};
        o[nb] = __builtin_amdgcn_mfma_f32_16x16x32_bf16(pa, bv, o[nb], 0, 0, 0);
      }
    }
  }
  // ---- normalize + store ctx (rows q = 4g+v, cols hd = nb*16+r) ----
#pragma unroll
  for (int v = 0; v < 4; ++v) {
    const float inv = 1.0f / lrow[v];
    const int qg = q0 + 4 * g + v;
#pragma unroll
    for (int nb = 0; nb < 4; ++nb)
      CTX[(size_t)qg * D_DIM + hoff + nb * 16 + r] = f2bf(o[nb][v] * inv);
  }
}

extern "C" void kernel_launch(void* const* d_in, const int* in_sizes, int n_in,
                              void* d_out, int out_size, void* d_ws, size_t ws_size,
                              hipStream_t stream) {
  const float* x  = (const float*)d_in[0];
  const float* Wq = (const float*)d_in[1];
  const float* Wk = (const float*)d_in[2];
  const float* Wv = (const float*)d_in[3];
  const float* Wo = (const float*)d_in[4];

  u16* xb  = (u16*)d_ws;                               // 4096x1024
  u16* Wqb = xb + (size_t)S_LEN * D_DIM;               // 1024x1024 each
  u16* Wkb = Wqb + (size_t)D_DIM * D_DIM;
  u16* Wvb = Wkb + (size_t)D_DIM * D_DIM;
  u16* Wob = Wvb + (size_t)D_DIM * D_DIM;
  u16* Qb  = Wob + (size_t)D_DIM * D_DIM;              // 4096x1024 each
  u16* Kb  = Qb + (size_t)S_LEN * D_DIM;
  u16* Vb  = Kb + (size_t)S_LEN * D_DIM;
  u16* Cb  = Vb + (size_t)S_LEN * D_DIM;

  cvt_bf16<<<S_LEN * D_DIM / 1024, 256, 0, stream>>>(x, xb, S_LEN * D_DIM);
  cvt_bf16<<<D_DIM * D_DIM / 1024, 256, 0, stream>>>(Wq, Wqb, D_DIM * D_DIM);
  cvt_bf16<<<D_DIM * D_DIM / 1024, 256, 0, stream>>>(Wk, Wkb, D_DIM * D_DIM);
  cvt_bf16<<<D_DIM * D_DIM / 1024, 256, 0, stream>>>(Wv, Wvb, D_DIM * D_DIM);
  cvt_bf16<<<D_DIM * D_DIM / 1024, 256, 0, stream>>>(Wo, Wob, D_DIM * D_DIM);

  gemm_qkv<<<dim3(48, 32), 256, 0, stream>>>(xb, Wqb, Wkb, Wvb, Qb, Kb, Vb);
  flash_attn<<<dim3(S_LEN / 64, NH), 256, 0, stream>>>(Qb, Kb, Vb, Cb);
  gemm_out<<<dim3(16, 32), 256, 0, stream>>>(Cb, Wob, (float*)d_out);
}

// Round 2
// 336.733 us; speedup vs baseline: 1.4830x; 1.4830x over previous
//
#include <hip/hip_runtime.h>

typedef unsigned short u16;
typedef __attribute__((ext_vector_type(8))) short s16x8;
typedef __attribute__((ext_vector_type(4))) short s16x4;
typedef __attribute__((ext_vector_type(4))) float f32x4;

#define S_LEN 4096
#define D_DIM 1024
#define NH    16
#define HDIM  64

#define AS1 __attribute__((address_space(1)))
#define AS3 __attribute__((address_space(3)))

__device__ __forceinline__ u16 f2bf(float f) {
  unsigned u = __float_as_uint(f);
  u += 0x7FFF + ((u >> 16) & 1);   // RNE
  return (u16)(u >> 16);
}

// async global->LDS, 16B per lane; LDS dest is wave-uniform (HW adds lane*16)
__device__ __forceinline__ void load_lds16(const void* g, void* l) {
  __builtin_amdgcn_global_load_lds((AS1 void*)g, (AS3 void*)l, 16, 0, 0);
}

__device__ __forceinline__ unsigned lds_addr32(const void* p) {
  return (unsigned)(unsigned long long)(AS3 const char*)p;
}

// hardware transpose read: lane l gets col (l&15), rows 4*(l>>4)+j of a
// row-major [16][16] bf16 subtile when per-lane addr = base + l*8
__device__ __forceinline__ s16x4 ds_read_tr16(unsigned addr) {
  s16x4 r;
  asm volatile("ds_read_b64_tr_b16 %0, %1" : "=v"(r) : "v"(addr));
  return r;
}

// ---------------- fp32 -> bf16 ----------------
__global__ __launch_bounds__(256) void cvt_bf16(const float* __restrict__ in,
                                                u16* __restrict__ out, int n) {
  int i = (blockIdx.x * 256 + threadIdx.x) * 4;
  if (i + 3 < n) {
    float4 v = *(const float4*)(in + i);
    ushort4 o;
    o.x = f2bf(v.x); o.y = f2bf(v.y); o.z = f2bf(v.z); o.w = f2bf(v.w);
    *(ushort4*)(out + i) = o;
  }
}

// 4 weight matrices in one launch (blockIdx.y selects)
__global__ __launch_bounds__(256) void cvt_w4(const float* __restrict__ w0,
                                              const float* __restrict__ w1,
                                              const float* __restrict__ w2,
                                              const float* __restrict__ w3,
                                              u16* o0, u16* o1, u16* o2, u16* o3) {
  const float* in; u16* out;
  switch (blockIdx.y) {
    case 0: in = w0; out = o0; break;
    case 1: in = w1; out = o1; break;
    case 2: in = w2; out = o2; break;
    default: in = w3; out = o3; break;
  }
  int i = (blockIdx.x * 256 + threadIdx.x) * 4;
  float4 v = *(const float4*)(in + i);
  ushort4 o;
  o.x = f2bf(v.x); o.y = f2bf(v.y); o.z = f2bf(v.z); o.w = f2bf(v.w);
  *(ushort4*)(out + i) = o;
}

// ---------------- GEMM: C[M,N] = A[M,K] * B[N,K]^T (bf16 in, fp32 acc) ----------
// tile 128x64, BK=32, 4 waves (2x2), double-buffered LDS + prefetch pipeline.
// LDS granule-XOR swizzle: granule (row,cg) holds src granule cg ^ ((row>>1)&3)
// -> ds_read_b128 2-way conflict (free) instead of 8-way.
struct GemmSmem { u16 As[2][128 * 32]; u16 Bs[2][64 * 32]; };

template <bool BF16_OUT>
__device__ __forceinline__ void gemm_tile(GemmSmem& sm, const u16* __restrict__ A,
                                          const u16* __restrict__ B,
                                          void* __restrict__ C, int m0, int n0,
                                          int N, int K) {
  const int t = threadIdx.x;
  const int l = t & 63, g = l >> 4, r = l & 15;
  const int w = t >> 6, wr = w >> 1, wc = w & 1;
  f32x4 acc[4][2] = {};

  auto stage = [&](int buf, int k0) {
#pragma unroll
    for (int i = 0; i < 2; ++i) {          // A: 512 granules of 16B
      const int gi = i * 256 + t;
      const int row = gi >> 2, cg = gi & 3;
      const int sc = cg ^ ((row >> 1) & 3);
      load_lds16(A + (size_t)(m0 + row) * K + k0 + sc * 8,
                 (char*)sm.As[buf] + (i * 256 + (t & 192)) * 16);
    }
    {                                       // B: 256 granules
      const int row = t >> 2, cg = t & 3;
      const int sc = cg ^ ((row >> 1) & 3);
      load_lds16(B + (size_t)(n0 + row) * K + k0 + sc * 8,
                 (char*)sm.Bs[buf] + (t & 192) * 16);
    }
  };

  stage(0, 0);
  __syncthreads();                          // drains vmcnt(0): buf0 ready
  int cur = 0;
  for (int k0 = 0; k0 < K; k0 += 32) {
    if (k0 + 32 < K) stage(cur ^ 1, k0 + 32);   // prefetch next K-step
    s16x8 a[4], b[2];
#pragma unroll
    for (int m = 0; m < 4; ++m) {
      const int row = wr * 64 + m * 16 + r;
      a[m] = *(const s16x8*)&sm.As[cur][row * 32 + ((g ^ ((row >> 1) & 3)) << 3)];
    }
#pragma unroll
    for (int n = 0; n < 2; ++n) {
      const int row = wc * 32 + n * 16 + r;
      b[n] = *(const s16x8*)&sm.Bs[cur][row * 32 + ((g ^ ((row >> 1) & 3)) << 3)];
    }
#pragma unroll
    for (int m = 0; m < 4; ++m)
#pragma unroll
      for (int n = 0; n < 2; ++n)
        acc[m][n] = __builtin_amdgcn_mfma_f32_16x16x32_bf16(a[m], b[n], acc[m][n], 0, 0, 0);
    __syncthreads();                        // prefetch landed + all reads of cur done
    cur ^= 1;
  }
  // D layout (verified): col = lane&15, row = 4*(lane>>4) + reg
#pragma unroll
  for (int m = 0; m < 4; ++m)
#pragma unroll
    for (int n = 0; n < 2; ++n)
#pragma unroll
      for (int v = 0; v < 4; ++v) {
        int row = m0 + wr * 64 + m * 16 + g * 4 + v;
        int col = n0 + wc * 32 + n * 16 + r;
        if (BF16_OUT)
          ((u16*)C)[(size_t)row * N + col] = f2bf(acc[m][n][v]);
        else
          ((float*)C)[(size_t)row * N + col] = acc[m][n][v];
      }
}

__global__ __launch_bounds__(256) void gemm_qkv(const u16* __restrict__ A,
                                                const u16* __restrict__ Bq,
                                                const u16* __restrict__ Bk,
                                                const u16* __restrict__ Bv,
                                                u16* Cq, u16* Ck, u16* Cv_) {
  __shared__ GemmSmem sm;
  const int which = blockIdx.x >> 4;   // 16 n-blocks of 64 per matrix
  const u16* B = which == 0 ? Bq : (which == 1 ? Bk : Bv);
  u16* C = which == 0 ? Cq : (which == 1 ? Ck : Cv_);
  gemm_tile<true>(sm, A, B, C, blockIdx.y * 128, (blockIdx.x & 15) * 64, D_DIM, D_DIM);
}

__global__ __launch_bounds__(256) void gemm_out(const u16* __restrict__ A,
                                                const u16* __restrict__ B,
                                                float* __restrict__ C) {
  __shared__ GemmSmem sm;
  gemm_tile<false>(sm, A, B, C, blockIdx.y * 128, blockIdx.x * 64, D_DIM, D_DIM);
}

// ---------------- causal flash attention ----------------
// block = 4 waves, QBLK=64 (16 q-rows/wave), KVBLK=64,
// double-buffered K/V staging with one-tile-ahead prefetch (T3-minimum pipeline).
__global__ __launch_bounds__(256) void flash_attn(const u16* __restrict__ Q,
                                                  const u16* __restrict__ Kg,
                                                  const u16* __restrict__ V,
                                                  u16* __restrict__ CTX) {
  const int h = blockIdx.y;
  const int qb = gridDim.x - 1 - blockIdx.x;  // big blocks first (causal tail)
  const int hoff = h * HDIM;
  const int t = threadIdx.x, w = t >> 6, l = t & 63, g = l >> 4, r = l & 15;
  const int q0 = qb * 64 + w * 16;

  __shared__ u16 Kt[2][64 * 64];    // [kv][hd], granule-XOR swizzled (row&7)
  __shared__ u16 Vt[2][16 * 256];   // 16 subtiles [16kv][16hd] for tr-reads
  __shared__ u16 Pt[4][16 * 68];    // per-wave P, pitch 68 u16 (bank-conflict-free b64)

  // Q fragments (A-operand): row = q0+r, k = hd contiguous-8
  const u16* qrow = Q + (size_t)(q0 + r) * D_DIM + hoff;
  const s16x8 aq0 = *(const s16x8*)(qrow + g * 8);
  const s16x8 aq1 = *(const s16x8*)(qrow + 32 + g * 8);

  f32x4 o[4] = {};
  float mrow[4], lrow[4];
#pragma unroll
  for (int v = 0; v < 4; ++v) { mrow[v] = -1e30f; lrow[v] = 0.f; }

  auto stage = [&](int buf, int tile) {
    const int kv0 = tile * 64;
#pragma unroll
    for (int i = 0; i < 2; ++i) {
      const int gi = i * 256 + t;
      const int krow = gi >> 3, c0 = gi & 7;
      load_lds16(Kg + (size_t)(kv0 + krow) * D_DIM + hoff + ((c0 ^ (krow & 7)) << 3),
                 (char*)Kt[buf] + (i * 256 + (t & 192)) * 16);
      const int vb = gi >> 5, vwg = gi & 31;
      load_lds16(V + (size_t)(kv0 + (vb >> 2) * 16 + (vwg >> 1)) * D_DIM + hoff +
                     (vb & 3) * 16 + (vwg & 1) * 8,
                 (char*)Vt[buf] + (i * 256 + (t & 192)) * 16);
    }
  };

  const int ntiles = qb + 1;
  stage(0, 0);
  __syncthreads();                  // buf0 ready
  int cur = 0;
  u16* Pw = Pt[w];
  const int qthr = w * 16 + 4 * g;

  for (int tile = 0; tile < ntiles; ++tile) {
    if (tile + 1 < ntiles) stage(cur ^ 1, tile + 1);   // prefetch next KV tile
    const u16* Kb = Kt[cur];
    const bool last = (tile == ntiles - 1);

    // ---- QK^T: S[16q x 64kv] ----
    f32x4 s[4];
    __builtin_amdgcn_s_setprio(1);
#pragma unroll
    for (int nb = 0; nb < 4; ++nb) {
      const int kr = nb * 16 + r;
      const int sw = kr & 7;
      s16x8 bk0 = *(const s16x8*)&Kb[kr * 64 + ((g ^ sw) << 3)];
      s16x8 bk1 = *(const s16x8*)&Kb[kr * 64 + (((4 + g) ^ sw) << 3)];
      f32x4 z = {0.f, 0.f, 0.f, 0.f};
      z = __builtin_amdgcn_mfma_f32_16x16x32_bf16(aq0, bk0, z, 0, 0, 0);
      z = __builtin_amdgcn_mfma_f32_16x16x32_bf16(aq1, bk1, z, 0, 0, 0);
      s[nb] = z;
    }
    __builtin_amdgcn_s_setprio(0);

    // ---- online softmax (rows q = 4g+v, cols kv = nb*16+r) ----
    float p[4][4], tmax[4];
#pragma unroll
    for (int v = 0; v < 4; ++v) {
#pragma unroll
      for (int nb = 0; nb < 4; ++nb) {
        float sv = s[nb][v] * 0.125f;
        if (last && (nb * 16 + r > qthr + v)) sv = -1e30f;   // causal mask
        p[nb][v] = sv;
      }
      tmax[v] = fmaxf(fmaxf(p[0][v], p[1][v]), fmaxf(p[2][v], p[3][v]));
    }
#pragma unroll
    for (int off = 1; off < 16; off <<= 1)
#pragma unroll
      for (int v = 0; v < 4; ++v)
        tmax[v] = fmaxf(tmax[v], __shfl_xor(tmax[v], off, 64));
    float fs[4], tsum[4];
#pragma unroll
    for (int v = 0; v < 4; ++v) {
      const float mnew = fmaxf(mrow[v], tmax[v]);
      fs[v] = __expf(mrow[v] - mnew);
      mrow[v] = mnew;
      float ps = 0.f;
#pragma unroll
      for (int nb = 0; nb < 4; ++nb) {
        const float pv = __expf(p[nb][v] - mnew);
        p[nb][v] = pv;
        ps += pv;
      }
      tsum[v] = ps;
    }
#pragma unroll
    for (int off = 1; off < 16; off <<= 1)
#pragma unroll
      for (int v = 0; v < 4; ++v) tsum[v] += __shfl_xor(tsum[v], off, 64);
#pragma unroll
    for (int v = 0; v < 4; ++v) {
      lrow[v] = lrow[v] * fs[v] + tsum[v];
#pragma unroll
      for (int nb = 0; nb < 4; ++nb) o[nb][v] *= fs[v];
#pragma unroll
      for (int nb = 0; nb < 4; ++nb)
        Pw[(4 * g + v) * 68 + nb * 16 + r] = f2bf(p[nb][v]);
    }

    // ---- PV: ctx += P[16q x 64kv] * V[64kv x 64hd], split in two k-halves ----
    const unsigned vbase = lds_addr32(Vt[cur]) + (unsigned)(l * 8);
#pragma unroll
    for (int kh = 0; kh < 2; ++kh) {
      s16x4 tv[4][2];
#pragma unroll
      for (int nb = 0; nb < 4; ++nb)
#pragma unroll
        for (int kb = 0; kb < 2; ++kb)
          tv[nb][kb] = ds_read_tr16(vbase + (unsigned)(((kh * 2 + kb) * 4 + nb) * 512));
      // P A-fragments: row=r, k = kh*32 + 4g+(e&3)+16*(e>>2)  (matches tr-read k-map)
      s16x4 plo = *(const s16x4*)&Pw[r * 68 + kh * 32 + g * 4];
      s16x4 phi = *(const s16x4*)&Pw[r * 68 + kh * 32 + 16 + g * 4];
      asm volatile("s_waitcnt lgkmcnt(0)" ::: "memory");
      __builtin_amdgcn_sched_barrier(0);
      s16x8 pa = {plo[0], plo[1], plo[2], plo[3], phi[0], phi[1], phi[2], phi[3]};
      __builtin_amdgcn_s_setprio(1);
#pragma unroll
      for (int nb = 0; nb < 4; ++nb) {
        s16x8 bv = {tv[nb][0][0], tv[nb][0][1], tv[nb][0][2], tv[nb][0][3],
                    tv[nb][1][0], tv[nb][1][1], tv[nb][1][2], tv[nb][1][3]};
        o[nb] = __builtin_amdgcn_mfma_f32_16x16x32_bf16(pa, bv, o[nb], 0, 0, 0);
      }
      __builtin_amdgcn_s_setprio(0);
    }
    __syncthreads();                // prefetch landed; all reads of cur done
    cur ^= 1;
  }

  // ---- normalize + store ctx (rows q = 4g+v, cols hd = nb*16+r) ----
#pragma unroll
  for (int v = 0; v < 4; ++v) {
    const float inv = 1.0f / lrow[v];
    const int qg = q0 + 4 * g + v;
#pragma unroll
    for (int nb = 0; nb < 4; ++nb)
      CTX[(size_t)qg * D_DIM + hoff + nb * 16 + r] = f2bf(o[nb][v] * inv);
  }
}

extern "C" void kernel_launch(void* const* d_in, const int* in_sizes, int n_in,
                              void* d_out, int out_size, void* d_ws, size_t ws_size,
                              hipStream_t stream) {
  const float* x  = (const float*)d_in[0];
  const float* Wq = (const float*)d_in[1];
  const float* Wk = (const float*)d_in[2];
  const float* Wv = (const float*)d_in[3];
  const float* Wo = (const float*)d_in[4];

  u16* xb  = (u16*)d_ws;                               // 4096x1024
  u16* Wqb = xb + (size_t)S_LEN * D_DIM;               // 1024x1024 each
  u16* Wkb = Wqb + (size_t)D_DIM * D_DIM;
  u16* Wvb = Wkb + (size_t)D_DIM * D_DIM;
  u16* Wob = Wvb + (size_t)D_DIM * D_DIM;
  u16* Qb  = Wob + (size_t)D_DIM * D_DIM;              // 4096x1024 each
  u16* Kb  = Qb + (size_t)S_LEN * D_DIM;
  u16* Vb  = Kb + (size_t)S_LEN * D_DIM;
  u16* Cb  = Vb + (size_t)S_LEN * D_DIM;

  cvt_bf16<<<S_LEN * D_DIM / 1024, 256, 0, stream>>>(x, xb, S_LEN * D_DIM);
  cvt_w4<<<dim3(D_DIM * D_DIM / 1024, 4), 256, 0, stream>>>(Wq, Wk, Wv, Wo,
                                                            Wqb, Wkb, Wvb, Wob);

  gemm_qkv<<<dim3(48, 32), 256, 0, stream>>>(xb, Wqb, Wkb, Wvb, Qb, Kb, Vb);
  flash_attn<<<dim3(S_LEN / 64, NH), 256, 0, stream>>>(Qb, Kb, Vb, Cb);
  gemm_out<<<dim3(16, 32), 256, 0, stream>>>(Cb, Wob, (float*)d_out);
}

// Round 3
// 252.226 us; speedup vs baseline: 1.9799x; 1.3350x over previous
//
#include <hip/hip_runtime.h>

typedef unsigned short u16;
typedef __attribute__((ext_vector_type(8))) short s16x8;
typedef __attribute__((ext_vector_type(4))) short s16x4;
typedef __attribute__((ext_vector_type(4))) float f32x4;

#define S_LEN 4096
#define D_DIM 1024
#define NH    16
#define HDIM  64
#define KVB   128

#define AS1 __attribute__((address_space(1)))
#define AS3 __attribute__((address_space(3)))

__device__ __forceinline__ u16 f2bf(float f) {
  unsigned u = __float_as_uint(f);
  u += 0x7FFF + ((u >> 16) & 1);   // RNE
  return (u16)(u >> 16);
}

// 1-op RNE f32->bf16 via packed convert (low half)
__device__ __forceinline__ u16 f2bf_pk(float f) {
  float r;
  asm("v_cvt_pk_bf16_f32 %0, %1, %1" : "=v"(r) : "v"(f));
  return (u16)(__float_as_uint(r) & 0xffffu);
}

// 2^x in one instruction
__device__ __forceinline__ float exp2fast(float x) {
  float r;
  asm("v_exp_f32 %0, %1" : "=v"(r) : "v"(x));
  return r;
}

// async global->LDS, 16B per lane; LDS dest is wave-uniform (HW adds lane*16)
__device__ __forceinline__ void load_lds16(const void* g, void* l) {
  __builtin_amdgcn_global_load_lds((AS1 void*)g, (AS3 void*)l, 16, 0, 0);
}

__device__ __forceinline__ unsigned lds_addr32(const void* p) {
  return (unsigned)(unsigned long long)(AS3 const char*)p;
}

// hardware transpose read: lane l gets col (l&15), rows 4*(l>>4)+j of a
// row-major [16][16] bf16 subtile when per-lane addr = base + l*8
__device__ __forceinline__ s16x4 ds_read_tr16(unsigned addr) {
  s16x4 r;
  asm volatile("ds_read_b64_tr_b16 %0, %1" : "=v"(r) : "v"(addr));
  return r;
}

// ---------------- fp32 -> bf16 ----------------
__global__ __launch_bounds__(256) void cvt_bf16(const float* __restrict__ in,
                                                u16* __restrict__ out, int n) {
  int i = (blockIdx.x * 256 + threadIdx.x) * 4;
  if (i + 3 < n) {
    float4 v = *(const float4*)(in + i);
    ushort4 o;
    o.x = f2bf(v.x); o.y = f2bf(v.y); o.z = f2bf(v.z); o.w = f2bf(v.w);
    *(ushort4*)(out + i) = o;
  }
}

__global__ __launch_bounds__(256) void cvt_w4(const float* __restrict__ w0,
                                              const float* __restrict__ w1,
                                              const float* __restrict__ w2,
                                              const float* __restrict__ w3,
                                              u16* o0, u16* o1, u16* o2, u16* o3) {
  const float* in; u16* out;
  switch (blockIdx.y) {
    case 0: in = w0; out = o0; break;
    case 1: in = w1; out = o1; break;
    case 2: in = w2; out = o2; break;
    default: in = w3; out = o3; break;
  }
  int i = (blockIdx.x * 256 + threadIdx.x) * 4;
  float4 v = *(const float4*)(in + i);
  ushort4 o;
  o.x = f2bf(v.x); o.y = f2bf(v.y); o.z = f2bf(v.z); o.w = f2bf(v.w);
  *(ushort4*)(out + i) = o;
}

// ---------------- GEMM: C[M,N] = cscale * A[M,K] * B[N,K]^T ----------------
// tile 128x64, BK=32, 4 waves (2x2), double-buffered LDS + prefetch pipeline.
struct GemmSmem { u16 As[2][128 * 32]; u16 Bs[2][64 * 32]; };

template <bool BF16_OUT>
__device__ __forceinline__ void gemm_tile(GemmSmem& sm, const u16* __restrict__ A,
                                          const u16* __restrict__ B,
                                          void* __restrict__ C, int m0, int n0,
                                          int N, int K, float cscale) {
  const int t = threadIdx.x;
  const int l = t & 63, g = l >> 4, r = l & 15;
  const int w = t >> 6, wr = w >> 1, wc = w & 1;
  f32x4 acc[4][2] = {};

  auto stage = [&](int buf, int k0) {
#pragma unroll
    for (int i = 0; i < 2; ++i) {          // A: 512 granules of 16B
      const int gi = i * 256 + t;
      const int row = gi >> 2, cg = gi & 3;
      const int sc = cg ^ ((row >> 1) & 3);
      load_lds16(A + (size_t)(m0 + row) * K + k0 + sc * 8,
                 (char*)sm.As[buf] + (i * 256 + (t & 192)) * 16);
    }
    {                                       // B: 256 granules
      const int row = t >> 2, cg = t & 3;
      const int sc = cg ^ ((row >> 1) & 3);
      load_lds16(B + (size_t)(n0 + row) * K + k0 + sc * 8,
                 (char*)sm.Bs[buf] + (t & 192) * 16);
    }
  };

  stage(0, 0);
  __syncthreads();
  int cur = 0;
  for (int k0 = 0; k0 < K; k0 += 32) {
    if (k0 + 32 < K) stage(cur ^ 1, k0 + 32);
    s16x8 a[4], b[2];
#pragma unroll
    for (int m = 0; m < 4; ++m) {
      const int row = wr * 64 + m * 16 + r;
      a[m] = *(const s16x8*)&sm.As[cur][row * 32 + ((g ^ ((row >> 1) & 3)) << 3)];
    }
#pragma unroll
    for (int n = 0; n < 2; ++n) {
      const int row = wc * 32 + n * 16 + r;
      b[n] = *(const s16x8*)&sm.Bs[cur][row * 32 + ((g ^ ((row >> 1) & 3)) << 3)];
    }
#pragma unroll
    for (int m = 0; m < 4; ++m)
#pragma unroll
      for (int n = 0; n < 2; ++n)
        acc[m][n] = __builtin_amdgcn_mfma_f32_16x16x32_bf16(a[m], b[n], acc[m][n], 0, 0, 0);
    __syncthreads();
    cur ^= 1;
  }
#pragma unroll
  for (int m = 0; m < 4; ++m)
#pragma unroll
    for (int n = 0; n < 2; ++n)
#pragma unroll
      for (int v = 0; v < 4; ++v) {
        int row = m0 + wr * 64 + m * 16 + g * 4 + v;
        int col = n0 + wc * 32 + n * 16 + r;
        float val = acc[m][n][v] * cscale;
        if (BF16_OUT)
          ((u16*)C)[(size_t)row * N + col] = f2bf(val);
        else
          ((float*)C)[(size_t)row * N + col] = val;
      }
}

// Q is pre-scaled by 0.125*log2(e) so attention works in exp2 domain
#define QSCALE 0.1803368801111204f

__global__ __launch_bounds__(256) void gemm_qkv(const u16* __restrict__ A,
                                                const u16* __restrict__ Bq,
                                                const u16* __restrict__ Bk,
                                                const u16* __restrict__ Bv,
                                                u16* Cq, u16* Ck, u16* Cv_) {
  __shared__ GemmSmem sm;
  const int which = blockIdx.x >> 4;
  const u16* B = which == 0 ? Bq : (which == 1 ? Bk : Bv);
  u16* C = which == 0 ? Cq : (which == 1 ? Ck : Cv_);
  const float cs = which == 0 ? QSCALE : 1.0f;
  gemm_tile<true>(sm, A, B, C, blockIdx.y * 128, (blockIdx.x & 15) * 64, D_DIM, D_DIM, cs);
}

__global__ __launch_bounds__(256) void gemm_out(const u16* __restrict__ A,
                                                const u16* __restrict__ B,
                                                float* __restrict__ C) {
  __shared__ GemmSmem sm;
  gemm_tile<false>(sm, A, B, C, blockIdx.y * 128, blockIdx.x * 64, D_DIM, D_DIM, 1.0f);
}

// ---------------- causal flash attention ----------------
// Diagonal-paired: block x handles q-tile (63-x) then q-tile x -> every block
// does exactly 33 KV-128 tiles (no tail). 4 waves, 16 q-rows/wave, KVBLK=128.
__global__ __launch_bounds__(256) void flash_attn(const u16* __restrict__ Q,
                                                  const u16* __restrict__ Kg,
                                                  const u16* __restrict__ V,
                                                  u16* __restrict__ CTX) {
  const int h = blockIdx.y;
  const int hoff = h * HDIM;
  const int t = threadIdx.x, w = t >> 6, l = t & 63, g = l >> 4, r = l & 15;

  __shared__ u16 Kt[2][KVB * 64];    // [kv][hd], granule-XOR swizzled (row&7)
  __shared__ u16 Vt[2][32 * 256];    // 32 subtiles [16kv][16hd] for tr-reads
  __shared__ u16 Pt[4][16 * 68];     // per-wave P (one 64-col half at a time)
  u16* Pw = Pt[w];

  auto stage = [&](int buf, int kv0) {
#pragma unroll
    for (int i = 0; i < 4; ++i) {
      const int gi = i * 256 + t;
      const int krow = gi >> 3, c0 = gi & 7;
      load_lds16(Kg + (size_t)(kv0 + krow) * D_DIM + hoff + ((c0 ^ (krow & 7)) << 3),
                 (char*)Kt[buf] + (i * 256 + (t & 192)) * 16);
      const int sv = gi >> 5, vo = gi & 31;
      load_lds16(V + (size_t)(kv0 + (sv >> 2) * 16 + (vo >> 1)) * D_DIM + hoff +
                     (sv & 3) * 16 + (vo & 1) * 8,
                 (char*)Vt[buf] + (i * 256 + (t & 192)) * 16);
    }
  };

#pragma unroll 1
  for (int run = 0; run < 2; ++run) {
    const int qt = run == 0 ? (63 - (int)blockIdx.x) : (int)blockIdx.x;
    const int q0 = qt * 64 + w * 16;

    const u16* qrow = Q + (size_t)(q0 + r) * D_DIM + hoff;
    const s16x8 aq0 = *(const s16x8*)(qrow + g * 8);
    const s16x8 aq1 = *(const s16x8*)(qrow + 32 + g * 8);

    f32x4 o[4] = {};
    float mrow[4], lrow[4];
#pragma unroll
    for (int v = 0; v < 4; ++v) { mrow[v] = -1e30f; lrow[v] = 0.f; }

    const int ntiles = (qt >> 1) + 1;
    stage(0, 0);
    __syncthreads();
    int cur = 0;

    for (int tile = 0; tile < ntiles; ++tile) {
      if (tile + 1 < ntiles) stage(cur ^ 1, (tile + 1) * KVB);
      const u16* Kb = Kt[cur];
      const bool lastT = (tile == ntiles - 1);

      // ---- QK^T: S[16q x 128kv] (Q pre-scaled, exp2 domain) ----
      f32x4 s[8];
      __builtin_amdgcn_s_setprio(1);
#pragma unroll
      for (int nb = 0; nb < 8; ++nb) {
        const int kr = nb * 16 + r;
        const int sw = kr & 7;
        s16x8 bk0 = *(const s16x8*)&Kb[kr * 64 + ((g ^ sw) << 3)];
        s16x8 bk1 = *(const s16x8*)&Kb[kr * 64 + (((4 + g) ^ sw) << 3)];
        f32x4 z = {0.f, 0.f, 0.f, 0.f};
        z = __builtin_amdgcn_mfma_f32_16x16x32_bf16(aq0, bk0, z, 0, 0, 0);
        z = __builtin_amdgcn_mfma_f32_16x16x32_bf16(aq1, bk1, z, 0, 0, 0);
        s[nb] = z;
      }
      __builtin_amdgcn_s_setprio(0);

      // ---- causal mask: only the diagonal tile pays for it ----
      if (lastT) {
        const int qrel = q0 + 4 * g - tile * KVB;
#pragma unroll
        for (int v = 0; v < 4; ++v)
#pragma unroll
          for (int nb = 0; nb < 8; ++nb)
            if (nb * 16 + r > qrel + v) s[nb][v] = -1e30f;
      }

      // ---- online softmax (rows q = 4g+v, cols kv = nb*16+r) ----
      float tmax[4];
#pragma unroll
      for (int v = 0; v < 4; ++v)
        tmax[v] = fmaxf(fmaxf(fmaxf(s[0][v], s[1][v]), fmaxf(s[2][v], s[3][v])),
                        fmaxf(fmaxf(s[4][v], s[5][v]), fmaxf(s[6][v], s[7][v])));
#pragma unroll
      for (int off = 1; off < 16; off <<= 1)
#pragma unroll
        for (int v = 0; v < 4; ++v)
          tmax[v] = fmaxf(tmax[v], __shfl_xor(tmax[v], off, 64));
      float fs[4], tsum[4];
#pragma unroll
      for (int v = 0; v < 4; ++v) {
        const float mnew = fmaxf(mrow[v], tmax[v]);
        fs[v] = exp2fast(mrow[v] - mnew);
        mrow[v] = mnew;
        float ps = 0.f;
#pragma unroll
        for (int nb = 0; nb < 8; ++nb) {
          const float pv = exp2fast(s[nb][v] - mnew);
          s[nb][v] = pv;
          ps += pv;
        }
        tsum[v] = ps;
      }
#pragma unroll
      for (int off = 1; off < 16; off <<= 1)
#pragma unroll
        for (int v = 0; v < 4; ++v) tsum[v] += __shfl_xor(tsum[v], off, 64);
#pragma unroll
      for (int v = 0; v < 4; ++v) {
        lrow[v] = lrow[v] * fs[v] + tsum[v];
#pragma unroll
        for (int nb = 0; nb < 4; ++nb) o[nb][v] *= fs[v];
      }

      // ---- PV in two 64-col halves: write P half, then 2 kh MFMA groups ----
      const unsigned vbase = lds_addr32(Vt[cur]) + (unsigned)(l * 8);
#pragma unroll
      for (int hh = 0; hh < 2; ++hh) {
#pragma unroll
        for (int v = 0; v < 4; ++v)
#pragma unroll
          for (int nb = 0; nb < 4; ++nb)
            Pw[(4 * g + v) * 68 + nb * 16 + r] = f2bf_pk(s[hh * 4 + nb][v]);
#pragma unroll
        for (int kq = 0; kq < 2; ++kq) {
          const int kh = hh * 2 + kq;           // kv 32-slice index, 0..3
          s16x4 tv[4][2];
#pragma unroll
          for (int nb = 0; nb < 4; ++nb)
#pragma unroll
            for (int kb = 0; kb < 2; ++kb)
              tv[nb][kb] = ds_read_tr16(vbase + (unsigned)(((kh * 2 + kb) * 4 + nb) * 512));
          s16x4 plo = *(const s16x4*)&Pw[r * 68 + kq * 32 + g * 4];
          s16x4 phi = *(const s16x4*)&Pw[r * 68 + kq * 32 + 16 + g * 4];
          asm volatile("s_waitcnt lgkmcnt(0)" ::: "memory");
          __builtin_amdgcn_sched_barrier(0);
          s16x8 pa = {plo[0], plo[1], plo[2], plo[3], phi[0], phi[1], phi[2], phi[3]};
          __builtin_amdgcn_s_setprio(1);
#pragma unroll
          for (int nb = 0; nb < 4; ++nb) {
            s16x8 bv = {tv[nb][0][0], tv[nb][0][1], tv[nb][0][2], tv[nb][0][3],
                        tv[nb][1][0], tv[nb][1][1], tv[nb][1][2], tv[nb][1][3]};
            o[nb] = __builtin_amdgcn_mfma_f32_16x16x32_bf16(pa, bv, o[nb], 0, 0, 0);
          }
          __builtin_amdgcn_s_setprio(0);
        }
      }
      __syncthreads();
      cur ^= 1;
    }

    // ---- normalize + store ctx ----
#pragma unroll
    for (int v = 0; v < 4; ++v) {
      const float inv = 1.0f / lrow[v];
      const int qg = q0 + 4 * g + v;
#pragma unroll
      for (int nb = 0; nb < 4; ++nb)
        CTX[(size_t)qg * D_DIM + hoff + nb * 16 + r] = f2bf_pk(o[nb][v] * inv);
    }
  }
}

extern "C" void kernel_launch(void* const* d_in, const int* in_sizes, int n_in,
                              void* d_out, int out_size, void* d_ws, size_t ws_size,
                              hipStream_t stream) {
  const float* x  = (const float*)d_in[0];
  const float* Wq = (const float*)d_in[1];
  const float* Wk = (const float*)d_in[2];
  const float* Wv = (const float*)d_in[3];
  const float* Wo = (const float*)d_in[4];

  u16* xb  = (u16*)d_ws;                               // 4096x1024
  u16* Wqb = xb + (size_t)S_LEN * D_DIM;               // 1024x1024 each
  u16* Wkb = Wqb + (size_t)D_DIM * D_DIM;
  u16* Wvb = Wkb + (size_t)D_DIM * D_DIM;
  u16* Wob = Wvb + (size_t)D_DIM * D_DIM;
  u16* Qb  = Wob + (size_t)D_DIM * D_DIM;              // 4096x1024 each
  u16* Kb  = Qb + (size_t)S_LEN * D_DIM;
  u16* Vb  = Kb + (size_t)S_LEN * D_DIM;
  u16* Cb  = Vb + (size_t)S_LEN * D_DIM;

  cvt_bf16<<<S_LEN * D_DIM / 1024, 256, 0, stream>>>(x, xb, S_LEN * D_DIM);
  cvt_w4<<<dim3(D_DIM * D_DIM / 1024, 4), 256, 0, stream>>>(Wq, Wk, Wv, Wo,
                                                            Wqb, Wkb, Wvb, Wob);

  gemm_qkv<<<dim3(48, 32), 256, 0, stream>>>(xb, Wqb, Wkb, Wvb, Qb, Kb, Vb);
  flash_attn<<<dim3(32, NH), 256, 0, stream>>>(Qb, Kb, Vb, Cb);
  gemm_out<<<dim3(16, 32), 256, 0, stream>>>(Cb, Wob, (float*)d_out);
}

// Round 5
// 212.652 us; speedup vs baseline: 2.3484x; 1.1861x over previous
//
#include <hip/hip_runtime.h>

typedef unsigned short u16;
typedef unsigned int u32;
typedef __attribute__((ext_vector_type(8))) short s16x8;
typedef __attribute__((ext_vector_type(4))) short s16x4;
typedef __attribute__((ext_vector_type(4))) float f32x4;

#define S_LEN 4096
#define D_DIM 1024
#define NH    16
#define HDIM  64
#define KVB   128

#define AS1 __attribute__((address_space(1)))
#define AS3 __attribute__((address_space(3)))

__device__ __forceinline__ u16 f2bf(float f) {
  unsigned u = __float_as_uint(f);
  u += 0x7FFF + ((u >> 16) & 1);   // RNE
  return (u16)(u >> 16);
}

// packed RNE f32x2 -> bf16x2 in one op
__device__ __forceinline__ u32 cvtpk2(float a, float b) {
  float r;
  asm("v_cvt_pk_bf16_f32 %0, %1, %2" : "=v"(r) : "v"(a), "v"(b));
  return __float_as_uint(r);
}

__device__ __forceinline__ u16 f2bf_pk(float f) {
  return (u16)(cvtpk2(f, f) & 0xffffu);
}

// 2^x in one instruction
__device__ __forceinline__ float exp2fast(float x) {
  float r;
  asm("v_exp_f32 %0, %1" : "=v"(r) : "v"(x));
  return r;
}

// async global->LDS, 16B per lane; LDS dest is wave-uniform (HW adds lane*16)
__device__ __forceinline__ void load_lds16(const void* g, void* l) {
  __builtin_amdgcn_global_load_lds((AS1 void*)g, (AS3 void*)l, 16, 0, 0);
}

__device__ __forceinline__ unsigned lds_addr32(const void* p) {
  return (unsigned)(unsigned long long)(AS3 const char*)p;
}

// hardware transpose read: on a row-major [16][16] bf16 subtile with per-lane
// addr = base + l*8, lane(g,r) receives elements [row=4g+j][col=r], j=0..3
__device__ __forceinline__ s16x4 ds_read_tr16(unsigned addr) {
  s16x4 r;
  asm volatile("ds_read_b64_tr_b16 %0, %1" : "=v"(r) : "v"(addr));
  return r;
}

// ---------------- fp32 -> bf16 ----------------
__global__ __launch_bounds__(256) void cvt_bf16(const float* __restrict__ in,
                                                u16* __restrict__ out, int n) {
  int i = (blockIdx.x * 256 + threadIdx.x) * 4;
  if (i + 3 < n) {
    float4 v = *(const float4*)(in + i);
    ushort4 o;
    o.x = f2bf(v.x); o.y = f2bf(v.y); o.z = f2bf(v.z); o.w = f2bf(v.w);
    *(ushort4*)(out + i) = o;
  }
}

__global__ __launch_bounds__(256) void cvt_w4(const float* __restrict__ w0,
                                              const float* __restrict__ w1,
                                              const float* __restrict__ w2,
                                              const float* __restrict__ w3,
                                              u16* o0, u16* o1, u16* o2, u16* o3) {
  const float* in; u16* out;
  switch (blockIdx.y) {
    case 0: in = w0; out = o0; break;
    case 1: in = w1; out = o1; break;
    case 2: in = w2; out = o2; break;
    default: in = w3; out = o3; break;
  }
  int i = (blockIdx.x * 256 + threadIdx.x) * 4;
  float4 v = *(const float4*)(in + i);
  ushort4 o;
  o.x = f2bf(v.x); o.y = f2bf(v.y); o.z = f2bf(v.z); o.w = f2bf(v.w);
  *(ushort4*)(out + i) = o;
}

// ---------------- GEMM: C[M,N] = cscale * A[M,K] * B[N,K]^T ----------------
// m97 structure: tile 128x128, BK=32, 4 waves (2x2), wave tile 64x64 (4x4 frags),
// 16 MFMA : 8 ds_read_b128 per K-step, double-buffered LDS + prefetch.
struct GemmSmem { u16 As[2][128 * 32]; u16 Bs[2][128 * 32]; };   // 32 KB

template <bool BF16_OUT>
__device__ __forceinline__ void gemm_tile(GemmSmem& sm, const u16* __restrict__ A,
                                          const u16* __restrict__ B,
                                          void* __restrict__ C, int m0, int n0,
                                          int N, int K, float cscale) {
  const int t = threadIdx.x;
  const int l = t & 63, g = l >> 4, r = l & 15;
  const int w = t >> 6, wr = w >> 1, wc = w & 1;
  f32x4 acc[4][4] = {};
  const int swz = (g ^ ((r >> 1) & 3)) << 3;   // read-side granule XOR

  auto stage = [&](int buf, int k0) {
#pragma unroll
    for (int i = 0; i < 2; ++i) {              // A,B: 512 granules of 16B each
      const int gi = i * 256 + t;
      const int row = gi >> 2, cg = gi & 3;
      const int sc = cg ^ ((row >> 1) & 3);
      load_lds16(A + (size_t)(m0 + row) * K + k0 + sc * 8,
                 (char*)sm.As[buf] + (i * 256 + (t & 192)) * 16);
      load_lds16(B + (size_t)(n0 + row) * K + k0 + sc * 8,
                 (char*)sm.Bs[buf] + (i * 256 + (t & 192)) * 16);
    }
  };

  stage(0, 0);
  __syncthreads();
  int cur = 0;
  for (int k0 = 0; k0 < K; k0 += 32) {
    if (k0 + 32 < K) stage(cur ^ 1, k0 + 32);
    s16x8 a[4], b[4];
#pragma unroll
    for (int m = 0; m < 4; ++m)
      a[m] = *(const s16x8*)&sm.As[cur][(wr * 64 + m * 16 + r) * 32 + swz];
#pragma unroll
    for (int n = 0; n < 4; ++n)
      b[n] = *(const s16x8*)&sm.Bs[cur][(wc * 64 + n * 16 + r) * 32 + swz];
#pragma unroll
    for (int m = 0; m < 4; ++m)
#pragma unroll
      for (int n = 0; n < 4; ++n)
        acc[m][n] = __builtin_amdgcn_mfma_f32_16x16x32_bf16(a[m], b[n], acc[m][n], 0, 0, 0);
    __syncthreads();
    cur ^= 1;
  }
  // D layout (verified): col = lane&15, row = 4*(lane>>4) + reg
#pragma unroll
  for (int m = 0; m < 4; ++m)
#pragma unroll
    for (int n = 0; n < 4; ++n)
#pragma unroll
      for (int v = 0; v < 4; ++v) {
        int row = m0 + wr * 64 + m * 16 + g * 4 + v;
        int col = n0 + wc * 64 + n * 16 + r;
        float val = acc[m][n][v] * cscale;
        if (BF16_OUT)
          ((u16*)C)[(size_t)row * N + col] = f2bf_pk(val);
        else
          ((float*)C)[(size_t)row * N + col] = val;
      }
}

// Q is pre-scaled by 0.125*log2(e) so attention works in exp2 domain
#define QSCALE 0.1803368801111204f

__global__ __launch_bounds__(256) void gemm_qkv(const u16* __restrict__ A,
                                                const u16* __restrict__ Bq,
                                                const u16* __restrict__ Bk,
                                                const u16* __restrict__ Bv,
                                                u16* Cq, u16* Ck, u16* Cv_) {
  __shared__ GemmSmem sm;
  const int which = blockIdx.x >> 3;           // 8 n-blocks of 128 per matrix
  const u16* B = which == 0 ? Bq : (which == 1 ? Bk : Bv);
  u16* C = which == 0 ? Cq : (which == 1 ? Ck : Cv_);
  const float cs = which == 0 ? QSCALE : 1.0f;
  gemm_tile<true>(sm, A, B, C, blockIdx.y * 128, (blockIdx.x & 7) * 128, D_DIM, D_DIM, cs);
}

__global__ __launch_bounds__(256) void gemm_out(const u16* __restrict__ A,
                                                const u16* __restrict__ B,
                                                float* __restrict__ C) {
  __shared__ GemmSmem sm;
  gemm_tile<false>(sm, A, B, C, blockIdx.y * 128, blockIdx.x * 128, D_DIM, D_DIM, 1.0f);
}

// ---------------- causal flash attention (swapped operands) ----------------
// Diagonal-paired: block x handles q-tile (63-x) then q-tile x (33 KV-128 tiles).
// 4 waves, 16 q-rows/wave. QK^T swapped -> lane holds S^T col (one q = lane&15,
// 32 kv values); softmax in-lane + 2 shuffles; P stays in registers and feeds
// swapped PV (O^T) directly under the tr-read k-map. No P LDS roundtrip.
__global__ __launch_bounds__(256) void flash_attn(const u16* __restrict__ Q,
                                                  const u16* __restrict__ Kg,
                                                  const u16* __restrict__ V,
                                                  u16* __restrict__ CTX) {
  const int h = blockIdx.y;
  const int hoff = h * HDIM;
  const int t = threadIdx.x, w = t >> 6, l = t & 63, g = l >> 4, r = l & 15;

  __shared__ u16 Kt[2][KVB * 64];    // [kv][hd], granule-XOR swizzled (row&7)
  __shared__ u16 Vt[2][32 * 256];    // 32 subtiles [16kv][16hd] for tr-reads

  auto stage = [&](int buf, int kv0) {
#pragma unroll
    for (int i = 0; i < 4; ++i) {
      const int gi = i * 256 + t;
      const int krow = gi >> 3, c0 = gi & 7;
      load_lds16(Kg + (size_t)(kv0 + krow) * D_DIM + hoff + ((c0 ^ (krow & 7)) << 3),
                 (char*)Kt[buf] + (i * 256 + (t & 192)) * 16);
      const int sv = gi >> 5, vo = gi & 31;
      load_lds16(V + (size_t)(kv0 + (sv >> 2) * 16 + (vo >> 1)) * D_DIM + hoff +
                     (sv & 3) * 16 + (vo & 1) * 8,
                 (char*)Vt[buf] + (i * 256 + (t & 192)) * 16);
    }
  };

#pragma unroll 1
  for (int run = 0; run < 2; ++run) {
    const int qt = run == 0 ? (63 - (int)blockIdx.x) : (int)blockIdx.x;
    const int q0 = qt * 64 + w * 16;

    // Q fragments (B-operand of swapped QK): row = q0+r, k = hd contiguous-8
    const u16* qrow = Q + (size_t)(q0 + r) * D_DIM + hoff;
    const s16x8 aq0 = *(const s16x8*)(qrow + g * 8);
    const s16x8 aq1 = *(const s16x8*)(qrow + 32 + g * 8);

    f32x4 o[4] = {};                 // O^T: hd = 16*hb + 4g+reg, q = r
    float mrun = -1e30f, lsum = 0.f;

    const int ntiles = (qt >> 1) + 1;
    stage(0, 0);
    __syncthreads();
    int cur = 0;

    for (int tile = 0; tile < ntiles; ++tile) {
      if (tile + 1 < ntiles) stage(cur ^ 1, (tile + 1) * KVB);
      const u16* Kb = Kt[cur];
      const bool lastT = (tile == ntiles - 1);

      // ---- S^T[128kv x 16q] = K·Q^T: s[nb][j] -> kv = 16nb+4g+j, q = r ----
      f32x4 s[8];
      __builtin_amdgcn_s_setprio(1);
#pragma unroll
      for (int nb = 0; nb < 8; ++nb) {
        const int kr = nb * 16 + r;
        const int sw = kr & 7;
        s16x8 bk0 = *(const s16x8*)&Kb[kr * 64 + ((g ^ sw) << 3)];
        s16x8 bk1 = *(const s16x8*)&Kb[kr * 64 + (((4 + g) ^ sw) << 3)];
        f32x4 z = {0.f, 0.f, 0.f, 0.f};
        z = __builtin_amdgcn_mfma_f32_16x16x32_bf16(bk0, aq0, z, 0, 0, 0);
        z = __builtin_amdgcn_mfma_f32_16x16x32_bf16(bk1, aq1, z, 0, 0, 0);
        s[nb] = z;
      }
      __builtin_amdgcn_s_setprio(0);

      // ---- causal mask (diagonal tile only); per-lane q threshold ----
      if (lastT) {
        const int qrel = q0 + r - tile * KVB;
#pragma unroll
        for (int nb = 0; nb < 8; ++nb)
#pragma unroll
          for (int j = 0; j < 4; ++j)
            if (16 * nb + 4 * g + j > qrel) s[nb][j] = -1e30f;
      }

      // ---- online softmax: in-lane over 32, then xor16+xor32 across g ----
      float tm = -1e30f;
#pragma unroll
      for (int nb = 0; nb < 8; ++nb) {
        float a0 = fmaxf(s[nb][0], s[nb][1]), a1 = fmaxf(s[nb][2], s[nb][3]);
        tm = fmaxf(tm, fmaxf(a0, a1));
      }
      tm = fmaxf(tm, __shfl_xor(tm, 16, 64));
      tm = fmaxf(tm, __shfl_xor(tm, 32, 64));
      const float mnew = fmaxf(mrun, tm);
      const float fs = exp2fast(mrun - mnew);
      mrun = mnew;
      float ps = 0.f;
#pragma unroll
      for (int nb = 0; nb < 8; ++nb)
#pragma unroll
        for (int j = 0; j < 4; ++j) {
          const float pv = exp2fast(s[nb][j] - mnew);
          s[nb][j] = pv;
          ps += pv;
        }
      ps += __shfl_xor(ps, 16, 64);
      ps += __shfl_xor(ps, 32, 64);
      lsum = lsum * fs + ps;
#pragma unroll
      for (int hb = 0; hb < 4; ++hb) {
        o[hb][0] *= fs; o[hb][1] *= fs; o[hb][2] *= fs; o[hb][3] *= fs;
      }

      // ---- pack P^T fragments: lane's own values ARE the B-operand ----
      // k-map (both sides): k = 4g + (e&3) + 16*(e>>2), kv = 32ks + k
      s16x8 pa[4];
#pragma unroll
      for (int ks = 0; ks < 4; ++ks) {
        union { u32 u[4]; s16x8 v; } pk_;
        pk_.u[0] = cvtpk2(s[2 * ks][0],     s[2 * ks][1]);
        pk_.u[1] = cvtpk2(s[2 * ks][2],     s[2 * ks][3]);
        pk_.u[2] = cvtpk2(s[2 * ks + 1][0], s[2 * ks + 1][1]);
        pk_.u[3] = cvtpk2(s[2 * ks + 1][2], s[2 * ks + 1][3]);
        pa[ks] = pk_.v;
      }

      // ---- PV swapped: o[hb] += V^T_frag[ks][hb] · pa[ks] ----
      // tr-reads issued in 8-read groups, 2 groups in flight, counted waits <=15
      const unsigned vbase = lds_addr32(Vt[cur]) + (unsigned)(l * 8);
      s16x4 tv[4][4][2];             // [ks][hb][half]
      auto issue_grp = [&](int ks) {
#pragma unroll
        for (int hb = 0; hb < 4; ++hb) {
          tv[ks][hb][0] = ds_read_tr16(vbase + (unsigned)(((2 * ks) * 4 + hb) * 512));
          tv[ks][hb][1] = ds_read_tr16(vbase + (unsigned)(((2 * ks + 1) * 4 + hb) * 512));
        }
      };
      issue_grp(0);
      issue_grp(1);
#pragma unroll
      for (int ks = 0; ks < 4; ++ks) {
        if (ks < 3) asm volatile("s_waitcnt lgkmcnt(8)" ::: "memory");
        else        asm volatile("s_waitcnt lgkmcnt(0)" ::: "memory");
        __builtin_amdgcn_sched_barrier(0);
        __builtin_amdgcn_s_setprio(1);
#pragma unroll
        for (int hb = 0; hb < 4; ++hb) {
          s16x8 vf = {tv[ks][hb][0][0], tv[ks][hb][0][1], tv[ks][hb][0][2], tv[ks][hb][0][3],
                      tv[ks][hb][1][0], tv[ks][hb][1][1], tv[ks][hb][1][2], tv[ks][hb][1][3]};
          o[hb] = __builtin_amdgcn_mfma_f32_16x16x32_bf16(vf, pa[ks], o[hb], 0, 0, 0);
        }
        __builtin_amdgcn_s_setprio(0);
        if (ks < 2) issue_grp(ks + 2);       // overlap next group with this MFMA
      }
      __syncthreads();               // prefetch landed; all reads of cur done
      cur ^= 1;
    }

    // ---- normalize + store O^T: lane(g,r): q = q0+r, hd = 16hb+4g+0..3 ----
    const float inv = 1.0f / lsum;
    u16* crow = CTX + (size_t)(q0 + r) * D_DIM + hoff + 4 * g;
#pragma unroll
    for (int hb = 0; hb < 4; ++hb) {
      uint2 pk_;
      pk_.x = cvtpk2(o[hb][0] * inv, o[hb][1] * inv);
      pk_.y = cvtpk2(o[hb][2] * inv, o[hb][3] * inv);
      *(uint2*)(crow + hb * 16) = pk_;
    }
  }
}

extern "C" void kernel_launch(void* const* d_in, const int* in_sizes, int n_in,
                              void* d_out, int out_size, void* d_ws, size_t ws_size,
                              hipStream_t stream) {
  const float* x  = (const float*)d_in[0];
  const float* Wq = (const float*)d_in[1];
  const float* Wk = (const float*)d_in[2];
  const float* Wv = (const float*)d_in[3];
  const float* Wo = (const float*)d_in[4];

  u16* xb  = (u16*)d_ws;                               // 4096x1024
  u16* Wqb = xb + (size_t)S_LEN * D_DIM;               // 1024x1024 each
  u16* Wkb = Wqb + (size_t)D_DIM * D_DIM;
  u16* Wvb = Wkb + (size_t)D_DIM * D_DIM;
  u16* Wob = Wvb + (size_t)D_DIM * D_DIM;
  u16* Qb  = Wob + (size_t)D_DIM * D_DIM;              // 4096x1024 each
  u16* Kb  = Qb + (size_t)S_LEN * D_DIM;
  u16* Vb  = Kb + (size_t)S_LEN * D_DIM;
  u16* Cb  = Vb + (size_t)S_LEN * D_DIM;

  cvt_bf16<<<S_LEN * D_DIM / 1024, 256, 0, stream>>>(x, xb, S_LEN * D_DIM);
  cvt_w4<<<dim3(D_DIM * D_DIM / 1024, 4), 256, 0, stream>>>(Wq, Wk, Wv, Wo,
                                                            Wqb, Wkb, Wvb, Wob);

  gemm_qkv<<<dim3(24, 32), 256, 0, stream>>>(xb, Wqb, Wkb, Wvb, Qb, Kb, Vb);
  flash_attn<<<dim3(32, NH), 256, 0, stream>>>(Qb, Kb, Vb, Cb);
  gemm_out<<<dim3(8, 32), 256, 0, stream>>>(Cb, Wob, (float*)d_out);
}

// Round 6
// 203.345 us; speedup vs baseline: 2.4559x; 1.0458x over previous
//
#include <hip/hip_runtime.h>

typedef unsigned short u16;
typedef unsigned int u32;
typedef __attribute__((ext_vector_type(8))) short s16x8;
typedef __attribute__((ext_vector_type(4))) short s16x4;
typedef __attribute__((ext_vector_type(4))) float f32x4;

#define S_LEN 4096
#define D_DIM 1024
#define NH    16
#define HDIM  64
#define KVB   128
#define QB    128

#define AS1 __attribute__((address_space(1)))
#define AS3 __attribute__((address_space(3)))

__device__ __forceinline__ u16 f2bf(float f) {
  unsigned u = __float_as_uint(f);
  u += 0x7FFF + ((u >> 16) & 1);   // RNE
  return (u16)(u >> 16);
}

// packed RNE f32x2 -> bf16x2 in one op
__device__ __forceinline__ u32 cvtpk2(float a, float b) {
  float r;
  asm("v_cvt_pk_bf16_f32 %0, %1, %2" : "=v"(r) : "v"(a), "v"(b));
  return __float_as_uint(r);
}

__device__ __forceinline__ u16 f2bf_pk(float f) {
  return (u16)(cvtpk2(f, f) & 0xffffu);
}

// 2^x in one instruction
__device__ __forceinline__ float exp2fast(float x) {
  float r;
  asm("v_exp_f32 %0, %1" : "=v"(r) : "v"(x));
  return r;
}

// async global->LDS, 16B per lane; LDS dest is wave-uniform (HW adds lane*16)
__device__ __forceinline__ void load_lds16(const void* g, void* l) {
  __builtin_amdgcn_global_load_lds((AS1 void*)g, (AS3 void*)l, 16, 0, 0);
}

__device__ __forceinline__ unsigned lds_addr32(const void* p) {
  return (unsigned)(unsigned long long)(AS3 const char*)p;
}

// hardware transpose read: on a row-major [16][16] bf16 subtile with per-lane
// addr = base + l*8, lane(g,r) receives elements [row=4g+j][col=r], j=0..3
__device__ __forceinline__ s16x4 ds_read_tr16(unsigned addr) {
  s16x4 r;
  asm volatile("ds_read_b64_tr_b16 %0, %1" : "=v"(r) : "v"(addr));
  return r;
}

// ---------------- fp32 -> bf16 (x in 4 slabs + 4 weights, one launch) --------
__global__ __launch_bounds__(256) void cvt_all(const float* __restrict__ x,
                                               const float* __restrict__ w0,
                                               const float* __restrict__ w1,
                                               const float* __restrict__ w2,
                                               const float* __restrict__ w3,
                                               u16* xb, u16* o0, u16* o1,
                                               u16* o2, u16* o3) {
  const float* in; u16* out;
  const int slab = blockIdx.y;
  switch (slab) {
    case 0: case 1: case 2: case 3:
      in = x + (size_t)slab * D_DIM * 1024; out = xb + (size_t)slab * D_DIM * 1024; break;
    case 4: in = w0; out = o0; break;
    case 5: in = w1; out = o1; break;
    case 6: in = w2; out = o2; break;
    default: in = w3; out = o3; break;
  }
  int i = (blockIdx.x * 256 + threadIdx.x) * 4;
  float4 v = *(const float4*)(in + i);
  ushort4 o;
  o.x = f2bf(v.x); o.y = f2bf(v.y); o.z = f2bf(v.z); o.w = f2bf(v.w);
  *(ushort4*)(out + i) = o;
}

// ---------------- GEMM: C[M,N] = cscale * A[M,K] * B[N,K]^T ----------------
// m97 structure: tile 128x128, BK=32, 4 waves (2x2), wave tile 64x64 (4x4 frags),
// 16 MFMA : 8 ds_read_b128 per K-step, double-buffered LDS + prefetch.
struct GemmSmem { u16 As[2][128 * 32]; u16 Bs[2][128 * 32]; };   // 32 KB

template <bool BF16_OUT>
__device__ __forceinline__ void gemm_tile(GemmSmem& sm, const u16* __restrict__ A,
                                          const u16* __restrict__ B,
                                          void* __restrict__ C, int m0, int n0,
                                          int N, int K, float cscale) {
  const int t = threadIdx.x;
  const int l = t & 63, g = l >> 4, r = l & 15;
  const int w = t >> 6, wr = w >> 1, wc = w & 1;
  f32x4 acc[4][4] = {};
  const int swz = (g ^ ((r >> 1) & 3)) << 3;   // read-side granule XOR

  auto stage = [&](int buf, int k0) {
#pragma unroll
    for (int i = 0; i < 2; ++i) {              // A,B: 512 granules of 16B each
      const int gi = i * 256 + t;
      const int row = gi >> 2, cg = gi & 3;
      const int sc = cg ^ ((row >> 1) & 3);
      load_lds16(A + (size_t)(m0 + row) * K + k0 + sc * 8,
                 (char*)sm.As[buf] + (i * 256 + (t & 192)) * 16);
      load_lds16(B + (size_t)(n0 + row) * K + k0 + sc * 8,
                 (char*)sm.Bs[buf] + (i * 256 + (t & 192)) * 16);
    }
  };

  stage(0, 0);
  __syncthreads();
  int cur = 0;
  for (int k0 = 0; k0 < K; k0 += 32) {
    if (k0 + 32 < K) stage(cur ^ 1, k0 + 32);
    s16x8 a[4], b[4];
#pragma unroll
    for (int m = 0; m < 4; ++m)
      a[m] = *(const s16x8*)&sm.As[cur][(wr * 64 + m * 16 + r) * 32 + swz];
#pragma unroll
    for (int n = 0; n < 4; ++n)
      b[n] = *(const s16x8*)&sm.Bs[cur][(wc * 64 + n * 16 + r) * 32 + swz];
#pragma unroll
    for (int m = 0; m < 4; ++m)
#pragma unroll
      for (int n = 0; n < 4; ++n)
        acc[m][n] = __builtin_amdgcn_mfma_f32_16x16x32_bf16(a[m], b[n], acc[m][n], 0, 0, 0);
    __syncthreads();
    cur ^= 1;
  }
  // D layout (verified): col = lane&15, row = 4*(lane>>4) + reg
#pragma unroll
  for (int m = 0; m < 4; ++m)
#pragma unroll
    for (int n = 0; n < 4; ++n)
#pragma unroll
      for (int v = 0; v < 4; ++v) {
        int row = m0 + wr * 64 + m * 16 + g * 4 + v;
        int col = n0 + wc * 64 + n * 16 + r;
        float val = acc[m][n][v] * cscale;
        if (BF16_OUT)
          ((u16*)C)[(size_t)row * N + col] = f2bf_pk(val);
        else
          ((float*)C)[(size_t)row * N + col] = val;
      }
}

// Q is pre-scaled by 0.125*log2(e) so attention works in exp2 domain
#define QSCALE 0.1803368801111204f

__global__ __launch_bounds__(256) void gemm_qkv(const u16* __restrict__ A,
                                                const u16* __restrict__ Bq,
                                                const u16* __restrict__ Bk,
                                                const u16* __restrict__ Bv,
                                                u16* Cq, u16* Ck, u16* Cv_) {
  __shared__ GemmSmem sm;
  // XCD-chunked swizzle: 768 blocks, 96 contiguous tiles per XCD
  const int f = blockIdx.y * 24 + blockIdx.x;
  const int tid = (f & 7) * 96 + (f >> 3);
  const int nby = tid / 24, nbx = tid % 24;
  const int which = nbx >> 3;                  // 8 n-blocks of 128 per matrix
  const u16* B = which == 0 ? Bq : (which == 1 ? Bk : Bv);
  u16* C = which == 0 ? Cq : (which == 1 ? Ck : Cv_);
  const float cs = which == 0 ? QSCALE : 1.0f;
  gemm_tile<true>(sm, A, B, C, nby * 128, (nbx & 7) * 128, D_DIM, D_DIM, cs);
}

__global__ __launch_bounds__(256) void gemm_out(const u16* __restrict__ A,
                                                const u16* __restrict__ B,
                                                float* __restrict__ C) {
  __shared__ GemmSmem sm;
  // XCD-chunked swizzle: 256 blocks, 32 contiguous tiles per XCD
  const int f = blockIdx.y * 8 + blockIdx.x;
  const int tid = (f & 7) * 32 + (f >> 3);
  gemm_tile<false>(sm, A, B, C, (tid >> 3) * 128, (tid & 7) * 128, D_DIM, D_DIM, 1.0f);
}

// ---------------- causal flash attention (swapped operands) ----------------
// QBLK=128, 8 waves (512 thr), 16 q-rows/wave; diagonal-paired: block x does
// q-tile (31-x) then q-tile x -> exactly 33 KV-128 tiles/block; 256 blocks
// (1/CU) -> serial chain per CU is 33 tiles, half of Round-5's 66.
__global__ __launch_bounds__(512) void flash_attn(const u16* __restrict__ Q,
                                                  const u16* __restrict__ Kg,
                                                  const u16* __restrict__ V,
                                                  u16* __restrict__ CTX) {
  const int h = blockIdx.y;
  const int hoff = h * HDIM;
  const int t = threadIdx.x, w = t >> 6, l = t & 63, g = l >> 4, r = l & 15;

  __shared__ u16 Kt[2][KVB * 64];    // [kv][hd], granule-XOR swizzled (row&7)
  __shared__ u16 Vt[2][32 * 256];    // 32 subtiles [16kv][16hd] for tr-reads

  auto stage = [&](int buf, int kv0) {
#pragma unroll
    for (int i = 0; i < 2; ++i) {    // 1024 granules each of K and V, 512 thr
      const int gi = i * 512 + t;
      const int krow = gi >> 3, c0 = gi & 7;
      load_lds16(Kg + (size_t)(kv0 + krow) * D_DIM + hoff + ((c0 ^ (krow & 7)) << 3),
                 (char*)Kt[buf] + (i * 512 + (t & 448)) * 16);
      const int sv = gi >> 5, vo = gi & 31;
      load_lds16(V + (size_t)(kv0 + (sv >> 2) * 16 + (vo >> 1)) * D_DIM + hoff +
                     (sv & 3) * 16 + (vo & 1) * 8,
                 (char*)Vt[buf] + (i * 512 + (t & 448)) * 16);
    }
  };

#pragma unroll 1
  for (int run = 0; run < 2; ++run) {
    const int qt = run == 0 ? (31 - (int)blockIdx.x) : (int)blockIdx.x;
    const int q0 = qt * QB + w * 16;

    // Q fragments (B-operand of swapped QK): row = q0+r, k = hd contiguous-8
    const u16* qrow = Q + (size_t)(q0 + r) * D_DIM + hoff;
    const s16x8 aq0 = *(const s16x8*)(qrow + g * 8);
    const s16x8 aq1 = *(const s16x8*)(qrow + 32 + g * 8);

    f32x4 o[4] = {};                 // O^T: hd = 16*hb + 4g+reg, q = r
    float mrun = -1e30f, lsum = 0.f;

    const int ntiles = qt + 1;
    stage(0, 0);
    __syncthreads();
    int cur = 0;

    for (int tile = 0; tile < ntiles; ++tile) {
      if (tile + 1 < ntiles) stage(cur ^ 1, (tile + 1) * KVB);
      const u16* Kb = Kt[cur];
      const bool lastT = (tile == ntiles - 1);

      // ---- S^T[128kv x 16q] = K·Q^T: s[nb][j] -> kv = 16nb+4g+j, q = r ----
      f32x4 s[8];
      __builtin_amdgcn_s_setprio(1);
#pragma unroll
      for (int nb = 0; nb < 8; ++nb) {
        const int kr = nb * 16 + r;
        const int sw = kr & 7;
        s16x8 bk0 = *(const s16x8*)&Kb[kr * 64 + ((g ^ sw) << 3)];
        s16x8 bk1 = *(const s16x8*)&Kb[kr * 64 + (((4 + g) ^ sw) << 3)];
        f32x4 z = {0.f, 0.f, 0.f, 0.f};
        z = __builtin_amdgcn_mfma_f32_16x16x32_bf16(bk0, aq0, z, 0, 0, 0);
        z = __builtin_amdgcn_mfma_f32_16x16x32_bf16(bk1, aq1, z, 0, 0, 0);
        s[nb] = z;
      }
      __builtin_amdgcn_s_setprio(0);

      // ---- causal mask (diagonal tile only); per-lane q threshold ----
      if (lastT) {
        const int qrel = q0 + r - tile * KVB;  // = w*16 + r on the diag tile
#pragma unroll
        for (int nb = 0; nb < 8; ++nb)
#pragma unroll
          for (int j = 0; j < 4; ++j)
            if (16 * nb + 4 * g + j > qrel) s[nb][j] = -1e30f;
      }

      // ---- online softmax: in-lane over 32, then xor16+xor32 across g ----
      float tm = -1e30f;
#pragma unroll
      for (int nb = 0; nb < 8; ++nb) {
        float a0 = fmaxf(s[nb][0], s[nb][1]), a1 = fmaxf(s[nb][2], s[nb][3]);
        tm = fmaxf(tm, fmaxf(a0, a1));
      }
      tm = fmaxf(tm, __shfl_xor(tm, 16, 64));
      tm = fmaxf(tm, __shfl_xor(tm, 32, 64));
      const float mnew = fmaxf(mrun, tm);
      const float fs = exp2fast(mrun - mnew);
      mrun = mnew;
      float ps = 0.f;
#pragma unroll
      for (int nb = 0; nb < 8; ++nb)
#pragma unroll
        for (int j = 0; j < 4; ++j) {
          const float pv = exp2fast(s[nb][j] - mnew);
          s[nb][j] = pv;
          ps += pv;
        }
      ps += __shfl_xor(ps, 16, 64);
      ps += __shfl_xor(ps, 32, 64);
      lsum = lsum * fs + ps;
#pragma unroll
      for (int hb = 0; hb < 4; ++hb) {
        o[hb][0] *= fs; o[hb][1] *= fs; o[hb][2] *= fs; o[hb][3] *= fs;
      }

      // ---- pack P^T fragments: lane's own values ARE the B-operand ----
      // k-map (both sides): k = 4g + (e&3) + 16*(e>>2), kv = 32ks + k
      s16x8 pa[4];
#pragma unroll
      for (int ks = 0; ks < 4; ++ks) {
        union { u32 u[4]; s16x8 v; } pk_;
        pk_.u[0] = cvtpk2(s[2 * ks][0],     s[2 * ks][1]);
        pk_.u[1] = cvtpk2(s[2 * ks][2],     s[2 * ks][3]);
        pk_.u[2] = cvtpk2(s[2 * ks + 1][0], s[2 * ks + 1][1]);
        pk_.u[3] = cvtpk2(s[2 * ks + 1][2], s[2 * ks + 1][3]);
        pa[ks] = pk_.v;
      }

      // ---- PV swapped: o[hb] += V^T_frag[ks][hb] · pa[ks] ----
      // tr-reads in 8-read groups, 2 groups in flight, counted waits <=15
      const unsigned vbase = lds_addr32(Vt[cur]) + (unsigned)(l * 8);
      s16x4 tv[4][4][2];             // [ks][hb][half]
      auto issue_grp = [&](int ks) {
#pragma unroll
        for (int hb = 0; hb < 4; ++hb) {
          tv[ks][hb][0] = ds_read_tr16(vbase + (unsigned)(((2 * ks) * 4 + hb) * 512));
          tv[ks][hb][1] = ds_read_tr16(vbase + (unsigned)(((2 * ks + 1) * 4 + hb) * 512));
        }
      };
      issue_grp(0);
      issue_grp(1);
#pragma unroll
      for (int ks = 0; ks < 4; ++ks) {
        if (ks < 3) asm volatile("s_waitcnt lgkmcnt(8)" ::: "memory");
        else        asm volatile("s_waitcnt lgkmcnt(0)" ::: "memory");
        __builtin_amdgcn_sched_barrier(0);
        __builtin_amdgcn_s_setprio(1);
#pragma unroll
        for (int hb = 0; hb < 4; ++hb) {
          s16x8 vf = {tv[ks][hb][0][0], tv[ks][hb][0][1], tv[ks][hb][0][2], tv[ks][hb][0][3],
                      tv[ks][hb][1][0], tv[ks][hb][1][1], tv[ks][hb][1][2], tv[ks][hb][1][3]};
          o[hb] = __builtin_amdgcn_mfma_f32_16x16x32_bf16(vf, pa[ks], o[hb], 0, 0, 0);
        }
        __builtin_amdgcn_s_setprio(0);
        if (ks < 2) issue_grp(ks + 2);       // overlap next group with this MFMA
      }
      __syncthreads();               // prefetch landed; all reads of cur done
      cur ^= 1;
    }

    // ---- normalize + store O^T: lane(g,r): q = q0+r, hd = 16hb+4g+0..3 ----
    const float inv = 1.0f / lsum;
    u16* crow = CTX + (size_t)(q0 + r) * D_DIM + hoff + 4 * g;
#pragma unroll
    for (int hb = 0; hb < 4; ++hb) {
      uint2 pk_;
      pk_.x = cvtpk2(o[hb][0] * inv, o[hb][1] * inv);
      pk_.y = cvtpk2(o[hb][2] * inv, o[hb][3] * inv);
      *(uint2*)(crow + hb * 16) = pk_;
    }
  }
}

extern "C" void kernel_launch(void* const* d_in, const int* in_sizes, int n_in,
                              void* d_out, int out_size, void* d_ws, size_t ws_size,
                              hipStream_t stream) {
  const float* x  = (const float*)d_in[0];
  const float* Wq = (const float*)d_in[1];
  const float* Wk = (const float*)d_in[2];
  const float* Wv = (const float*)d_in[3];
  const float* Wo = (const float*)d_in[4];

  u16* xb  = (u16*)d_ws;                               // 4096x1024
  u16* Wqb = xb + (size_t)S_LEN * D_DIM;               // 1024x1024 each
  u16* Wkb = Wqb + (size_t)D_DIM * D_DIM;
  u16* Wvb = Wkb + (size_t)D_DIM * D_DIM;
  u16* Wob = Wvb + (size_t)D_DIM * D_DIM;
  u16* Qb  = Wob + (size_t)D_DIM * D_DIM;              // 4096x1024 each
  u16* Kb  = Qb + (size_t)S_LEN * D_DIM;
  u16* Vb  = Kb + (size_t)S_LEN * D_DIM;
  u16* Cb  = Vb + (size_t)S_LEN * D_DIM;

  cvt_all<<<dim3(1024, 8), 256, 0, stream>>>(x, Wq, Wk, Wv, Wo,
                                             xb, Wqb, Wkb, Wvb, Wob);
  gemm_qkv<<<dim3(24, 32), 256, 0, stream>>>(xb, Wqb, Wkb, Wvb, Qb, Kb, Vb);
  flash_attn<<<dim3(S_LEN / QB / 2, NH), 512, 0, stream>>>(Qb, Kb, Vb, Cb);
  gemm_out<<<dim3(8, 32), 256, 0, stream>>>(Cb, Wob, (float*)d_out);
}